// Round 1
// 127.561 us; speedup vs baseline: 1.0034x; 1.0034x over previous
//
#include <hip/hip_runtime.h>
#include <hip/hip_bf16.h>

// x[16,32,32,32,32] f32, w[32,64,3,3,3] f32, b[64] f32
// ConvTranspose3d(s=2,p=1,k=3) -> (+bias)*0.5 -> maxpool2 -> mean -> clamp[0,1] -> out[16,64]
//
// Window algebra (validated R0/R1): window w covers conv outputs {2w,2w+1}/dim,
// inputs {w,w+1}/dim; per-dim (delta,k,parity): (0,1,0) (0,2,1) (1,0,1). No bounds checks.
// MFMA 16x16x32 bf16: M=16 ww-windows, N=16 co, K=32=Cin (layouts verified R1).
//
// R7: LDS-BW + pipeline restructure (theory: LDS pipe ~76% busy was capping MfmaUtil at 44%):
//  - __launch_bounds__(256,2): accept 2 waves/SIMD (matches measured occupancy anyway),
//    giving a 256-reg budget so Bf[27] (108 regs) + frags + 9 accs stay resident.
//  - rolling A-frag reuse: rows advance by 1 per window -> only 4 new ds_read_b128
//    per window (36/half = the minimum; was 64/half). FA=row win, FB=row win+1,
//    FC=prefetch row win+2 issued before the MFMA burst.
//  - all 27 MFMAs interleaved round-robin over 9 independent chains
//    (Ca,Cb=class(1,1,1) split by kd; Cc..Ci per parity class), ONE combine at end
//    (max3-shaped fmax tree) -> no per-class VALU drains between MFMA clusters.
// Frag rule: tap (kd,kh,kw) uses frag[dd=(kd==0)][dw=(kw==0)] of row win+(kh==0).
//
// ws: [0,4096)B accS[16][64] f32; [4096,...) wB bf16 [cotile4][T27][lane64][j8],
// T in exact consumption order (see TAP tables).

typedef __bf16 bf16x8 __attribute__((ext_vector_type(8)));
typedef float  f32x4  __attribute__((ext_vector_type(4)));
typedef unsigned short ushort_t;
typedef ushort_t ushort8 __attribute__((ext_vector_type(8)));

#define NWIN 29791  // 31^3

__device__ inline ushort_t f2bf(float f) {
    unsigned u = __builtin_bit_cast(unsigned, f);
    u += 0x7FFFu + ((u >> 16) & 1u);   // RNE
    return (ushort_t)(u >> 16);
}

// Consumption-order tap list (kd,kh,kw) for T=0..26
__device__ __constant__ const unsigned char TKD[27] = {2,0,2,0,2,0,2,0, 1,0,1,2,1,0,1,2, 0,1,2,1,0,1,2,1, 0,1,2};
__device__ __constant__ const unsigned char TKH[27] = {0,0,0,0,2,2,2,2, 0,1,0,1,2,1,2,1, 0,1,0,0,2,1,2,2, 1,1,1};
__device__ __constant__ const unsigned char TKW[27] = {0,0,2,2,0,0,2,2, 0,0,2,0,0,2,2,2, 1,0,1,1,1,2,1,1, 1,1,1};

__global__ __launch_bounds__(256) void prep_kernel(const float* __restrict__ w,
                                                   float* __restrict__ ws) {
    int idx = blockIdx.x * 256 + threadIdx.x;
    if (idx < 1024) ws[idx] = 0.f;
    if (idx < 55296) {
        ushort_t* wB = (ushort_t*)((char*)ws + 4096);
        int j = idx & 7;
        int l = (idx >> 3) & 63;
        int q = idx >> 9;           // [0,108) = c*27+T
        int T = q % 27;
        int c = q / 27;
        int ci = ((l >> 4) << 3) + j;
        int co = (c << 4) + (l & 15);
        int k3 = TKD[T] * 9 + TKH[T] * 3 + TKW[T];
        wB[idx] = f2bf(w[(ci * 64 + co) * 27 + k3]);
    }
}

#define MFMA(A, B, C) __builtin_amdgcn_mfma_f32_16x16x32_bf16((A), (B), (C), 0, 0, 0)

// grid = 16 b * 31 wd * 4 whg, 256 threads
__global__ __launch_bounds__(256, 2) void main_kernel(const float* __restrict__ x,
                                                      const float* __restrict__ ws_ro,
                                                      float* __restrict__ accS) {
    __shared__ ushort_t xT[18432];  // [dd2][hh9][w32][ci32] bf16, s = kq ^ ((w>>1)&3)

    int bid = blockIdx.x;
    int b   = bid / 124;            // 31*4
    int r   = bid - b * 124;
    int wd  = r >> 2;               // [0,31)
    int whg = r & 3;                // wh group of 8
    int tid = threadIdx.x;
    int lane = tid & 63;
    int wave = tid >> 6;
    int uw   = __builtin_amdgcn_readfirstlane(wave);

    // ---- this wave's 27 weight B-frags (consumption order) -> regs, resident for kernel life
    const bf16x8* wBv = (const bf16x8*)((const char*)ws_ro + 4096);
    bf16x8 Bf[27];
#pragma unroll
    for (int t = 0; t < 27; ++t) Bf[t] = wBv[(uw * 27 + t) * 64 + lane];

    // ---- stage: wave uw stages ci planes [8uw,8uw+8); lane = (dd=lane>>5, w=lane&31)
    {
        int dd = lane >> 5;
        int wl = lane & 31;
        const float* xb = x + ((size_t)(b * 32 + uw * 8)) * 32768u
                            + ((size_t)(wd + 1) << 10) + ((size_t)(whg << 3) << 5);
        int voff = (dd - 1) * 1024 + wl;
        int ro8  = (whg == 3) ? 7 * 32 : 8 * 32;          // clamped last row (masked window only)
        int s    = uw ^ ((wl >> 1) & 3);
        ushort_t* dst = &xT[((dd * 9) << 10) + (wl << 5) + (s << 3)];
#pragma unroll
        for (int rr = 0; rr < 9; ++rr) {
            int ro = (rr < 8) ? rr * 32 : ro8;
            float v[8];
#pragma unroll
            for (int i = 0; i < 8; ++i) v[i] = xb[(size_t)i * 32768u + voff + ro];
            ushort8 pk;
#pragma unroll
            for (int i = 0; i < 4; ++i) {
                __hip_bfloat162 p2 = __float22bfloat162_rn(float2{v[2 * i], v[2 * i + 1]});
                pk[2 * i]     = __builtin_bit_cast(ushort_t, p2.x);
                pk[2 * i + 1] = __builtin_bit_cast(ushort_t, p2.y);
            }
            *(ushort8*)&dst[rr << 10] = pk;
        }
    }
    __syncthreads();

    int m  = lane & 15;
    int kq = lane >> 4;
    float runsum = 0.f;
    const f32x4 Z = (f32x4){0.f, 0.f, 0.f, 0.f};

#pragma unroll 1
    for (int half = 0; half < 2; ++half) {
        int wbase = half << 4;
        int w0 = wbase + m;                    // <= 31
        int w1 = w0 + 1; if (w1 > 31) w1 = 31; // garbage -> window 31, masked
        int col0 = (w0 << 5) + ((kq ^ ((w0 >> 1) & 3)) << 3);
        int col1 = (w1 << 5) + ((kq ^ ((w1 >> 1) & 3)) << 3);
        const ushort_t* p0 = &xT[col0];
        const ushort_t* p1 = &xT[col1];

        // preload rows 0 (FA) and 1 (FB); indices [dd][dw], dw=1 <-> w-delta 1 (col1)
        bf16x8 FA[2][2], FB[2][2];
#pragma unroll
        for (int dd = 0; dd < 2; ++dd) {
            FA[dd][0] = *(const bf16x8*)&p0[((dd * 9 + 0) << 10)];
            FA[dd][1] = *(const bf16x8*)&p1[((dd * 9 + 0) << 10)];
            FB[dd][0] = *(const bf16x8*)&p0[((dd * 9 + 1) << 10)];
            FB[dd][1] = *(const bf16x8*)&p1[((dd * 9 + 1) << 10)];
        }

#pragma unroll
        for (int win = 0; win < 8; ++win) {
            // prefetch row win+2 (consumed next window) before the MFMA burst
            bf16x8 FC[2][2];
            if (win < 7) {
#pragma unroll
                for (int dd = 0; dd < 2; ++dd) {
                    FC[dd][0] = *(const bf16x8*)&p0[((dd * 9 + win + 2) << 10)];
                    FC[dd][1] = *(const bf16x8*)&p1[((dd * 9 + win + 2) << 10)];
                }
            }

            // 27 MFMAs, 9 independent chains, round-robin issue.
            // FA = row win (kh in {1,2}); FB = row win+1 (kh==0).
            f32x4 Ca, Cb, Cc, Cd, Ce, Cf, Cg, Ch, Ci;
            // round 1 (chain starts)
            Ca = MFMA(FB[0][1], Bf[0],  Z);   // T0  (2,0,0)
            Cb = MFMA(FB[1][1], Bf[1],  Z);   // T1  (0,0,0)
            Cc = MFMA(FB[0][1], Bf[8],  Z);   // T8  (1,0,0)
            Cd = MFMA(FA[1][1], Bf[9],  Z);   // T9  (0,1,0)
            Ce = MFMA(FB[1][0], Bf[16], Z);   // T16 (0,0,1)
            Cf = MFMA(FA[0][1], Bf[17], Z);   // T17 (1,1,0)
            Cg = MFMA(FB[0][0], Bf[19], Z);   // T19 (1,0,1)
            Ch = MFMA(FA[1][0], Bf[24], Z);   // T24 (0,1,1)
            Ci = MFMA(FA[0][0], Bf[25], Z);   // T25 (1,1,1)
            // round 2
            Ca = MFMA(FB[0][0], Bf[2],  Ca);  // T2  (2,0,2)
            Cb = MFMA(FB[1][0], Bf[3],  Cb);  // T3  (0,0,2)
            Cc = MFMA(FB[0][0], Bf[10], Cc);  // T10 (1,0,2)
            Cd = MFMA(FA[0][1], Bf[11], Cd);  // T11 (2,1,0)
            Ce = MFMA(FB[0][0], Bf[18], Ce);  // T18 (2,0,1)
            Cf = MFMA(FA[0][0], Bf[21], Cf);  // T21 (1,1,2)
            Cg = MFMA(FA[0][0], Bf[23], Cg);  // T23 (1,2,1)
            Ch = MFMA(FA[0][0], Bf[26], Ch);  // T26 (2,1,1)
            // round 3
            Ca = MFMA(FA[0][1], Bf[4],  Ca);  // T4  (2,2,0)
            Cb = MFMA(FA[1][1], Bf[5],  Cb);  // T5  (0,2,0)
            Cc = MFMA(FA[0][1], Bf[12], Cc);  // T12 (1,2,0)
            Cd = MFMA(FA[1][0], Bf[13], Cd);  // T13 (0,1,2)
            Ce = MFMA(FA[1][0], Bf[20], Ce);  // T20 (0,2,1)
            // round 4
            Ca = MFMA(FA[0][0], Bf[6],  Ca);  // T6  (2,2,2)
            Cb = MFMA(FA[1][0], Bf[7],  Cb);  // T7  (0,2,2)
            Cc = MFMA(FA[0][0], Bf[14], Cc);  // T14 (1,2,2)
            Cd = MFMA(FA[0][0], Bf[15], Cd);  // T15 (2,1,2)
            Ce = MFMA(FA[0][0], Bf[22], Ce);  // T22 (2,2,1)

            // single combine: 1 add + max3-shaped tree (8 conv outputs per window)
            f32x4 mx;
#pragma unroll
            for (int i = 0; i < 4; ++i) {
                float s0 = Ca[i] + Cb[i];                       // class (1,1,1) sum
                float m1 = fmaxf(fmaxf(s0, Cc[i]), Cd[i]);      // v_max3
                float m2 = fmaxf(fmaxf(Ce[i], Cf[i]), Cg[i]);   // v_max3
                float m3 = fmaxf(fmaxf(Ch[i], Ci[i]), m1);      // v_max3
                mx[i] = fmaxf(m2, m3);
            }

            // masked accumulate: wh = 8*whg + win, rows ww = wbase + kq*4 + rr
            int wh = (whg << 3) + win;
            if (wh < 31) {
#pragma unroll
                for (int rr = 0; rr < 4; ++rr) {
                    int ww = wbase + (kq << 2) + rr;
                    if (ww < 31) runsum += mx[rr];
                }
            }

            // rotate rows (pure SSA renaming under full unroll)
            if (win < 7) {
#pragma unroll
                for (int dd = 0; dd < 2; ++dd)
#pragma unroll
                    for (int dw = 0; dw < 2; ++dw) {
                        FA[dd][dw] = FB[dd][dw];
                        FB[dd][dw] = FC[dd][dw];
                    }
            }
        }
    }

    // lanes with same n=(lane&15) hold partials for the same co
    runsum += __shfl_xor(runsum, 16, 64);
    runsum += __shfl_xor(runsum, 32, 64);
    if (lane < 16) atomicAdd(&accS[(b << 6) + (wave << 4) + lane], runsum);
}

__global__ __launch_bounds__(256) void finalize_kernel(const float* __restrict__ accS,
                                                       const float* __restrict__ bias,
                                                       float* __restrict__ out) {
    int i = blockIdx.x * 256 + threadIdx.x;
    if (i < 1024) {
        int co = i & 63;
        float v = (accS[i] * (1.f / (float)NWIN) + bias[co]) * 0.5f;
        v = fminf(fmaxf(v, 0.f), 1.f);
        out[i] = v;
    }
}

extern "C" void kernel_launch(void* const* d_in, const int* in_sizes, int n_in,
                              void* d_out, int out_size, void* d_ws, size_t ws_size,
                              hipStream_t stream) {
    const float* x    = (const float*)d_in[0];
    const float* w    = (const float*)d_in[1];
    const float* bias = (const float*)d_in[2];
    float* out = (float*)d_out;
    float* ws  = (float*)d_ws;

    prep_kernel<<<216, 256, 0, stream>>>(w, ws);
    main_kernel<<<16 * 31 * 4, 256, 0, stream>>>(x, ws, ws);
    finalize_kernel<<<4, 256, 0, stream>>>(ws, bias, out);
}